// Round 2
// baseline (390.742 us; speedup 1.0000x reference)
//
#include <hip/hip_runtime.h>
#include <hip/hip_bf16.h>

// EdgeBlock: out = relu(concat(xn[src], xn[dst], xe) @ W1 + b1) @ W2 + b2
// Strategy: bf16 MFMA (16x16x32), fused gather+GEMM1+ReLU+GEMM2 per 64-edge tile.
// Prep kernels transpose-convert W1/W2 to bf16 [n][k] and convert x_node to bf16 in d_ws.

typedef __attribute__((ext_vector_type(8))) short short8;   // 8 bf16 = 4 VGPR (MFMA A/B frag)
typedef __attribute__((ext_vector_type(4))) float f32x4;    // MFMA C/D frag

#define LDA 72    // A tile row stride (bf16 elems), 64+8 pad
#define LDB 72    // Bt tile row stride
#define LDH 264   // H tile row stride, 256+8 pad

// RNE f32 -> bf16 (no type-layout dependence on __hip_bfloat16 internals)
__device__ __forceinline__ unsigned short f2b(float f) {
  unsigned int u = __float_as_uint(f);
  unsigned int r = (u + 0x7FFFu + ((u >> 16) & 1u)) >> 16;
  return (unsigned short)r;
}

__global__ void transpose_w_kernel(const float* __restrict__ w,
                                   unsigned short* __restrict__ wt,
                                   int K, int N) {
  int i = blockIdx.x * 256 + threadIdx.x;   // i = n*K + k (output-contiguous)
  if (i >= K * N) return;
  int n = i / K;
  int k = i - n * K;
  wt[i] = f2b(w[(size_t)k * N + n]);
}

__global__ void conv_bf16_kernel(const float* __restrict__ x,
                                 unsigned short* __restrict__ y, int n4) {
  int i = blockIdx.x * 256 + threadIdx.x;
  if (i >= n4) return;
  float4 v = ((const float4*)x)[i];
  ushort4 u;
  u.x = f2b(v.x); u.y = f2b(v.y); u.z = f2b(v.z); u.w = f2b(v.w);
  ((ushort4*)y)[i] = u;
}

__global__ __launch_bounds__(256, 2) void edge_mlp_kernel(
    const float* __restrict__ xnode, const float* __restrict__ xedge,
    const int* __restrict__ eidx,
    const unsigned short* __restrict__ nodeb, int use_nodeb,
    const unsigned short* __restrict__ wt1, const float* __restrict__ b1,
    const unsigned short* __restrict__ wt2, const float* __restrict__ b2,
    float* __restrict__ out, int E) {
  __shared__ __align__(16) unsigned short As[64 * LDA];    //  9.2 KB
  __shared__ __align__(16) unsigned short Bs[256 * LDB];   // 36.9 KB
  __shared__ __align__(16) unsigned short Hs[64 * LDH];    // 33.8 KB

  const int t = threadIdx.x;
  const int w = t >> 6;        // wave 0..3 -> output cols [64w, 64w+64)
  const int l = t & 63;
  const int lr = l & 15;       // frag M/N lane index
  const int lk = l >> 4;       // frag K group

  const int ar = t >> 2;       // A-staging row (0..63)
  const int ac = t & 3;        // A-staging col group (16 elems each)

  const int ebase = blockIdx.x * 64;
  int e = ebase + ar;
  if (e >= E) e = E - 1;       // clamp tail (stores guarded later)
  const int isrc = eidx[e];
  const int idst = eidx[E + e];

  f32x4 acc[4][4];
#pragma unroll
  for (int i = 0; i < 4; ++i)
#pragma unroll
    for (int j = 0; j < 4; ++j) acc[i][j] = (f32x4)0.0f;

  // ---------------- GEMM1: [64,768] @ [768,256] ----------------
  for (int kc = 0; kc < 12; ++kc) {
    const int seg = kc >> 2;           // 0:src 1:dst 2:edge
    const int kin = (kc & 3) * 64;     // k offset within segment

    // stage A chunk [64][64] bf16
    if (use_nodeb && seg < 2) {
      const int row = (seg == 0) ? isrc : idst;
      const unsigned short* sp = nodeb + (size_t)row * 256 + kin + ac * 16;
      uint4 v0 = *(const uint4*)(sp);
      uint4 v1 = *(const uint4*)(sp + 8);
      *(uint4*)&As[ar * LDA + ac * 16] = v0;
      *(uint4*)&As[ar * LDA + ac * 16 + 8] = v1;
    } else {
      const float* sp =
          ((seg == 0) ? xnode + (size_t)isrc * 256
                      : (seg == 1) ? xnode + (size_t)idst * 256
                                   : xedge + (size_t)e * 256) + kin + ac * 16;
#pragma unroll
      for (int q = 0; q < 4; ++q) {
        float4 v = *(const float4*)(sp + q * 4);
        ushort4 u;
        u.x = f2b(v.x); u.y = f2b(v.y); u.z = f2b(v.z); u.w = f2b(v.w);
        *(ushort4*)&As[ar * LDA + ac * 16 + q * 4] = u;
      }
    }

    // stage B chunk: Wt1[n][k] rows n=0..255, k in [kc*64, kc*64+64)
    {
      const unsigned short* wp = wt1 + kc * 64 + (t & 7) * 8;
      const int n0 = t >> 3;
#pragma unroll
      for (int i = 0; i < 8; ++i) {
        const int n = n0 + 32 * i;
        uint4 v = *(const uint4*)(wp + (size_t)n * 768);
        *(uint4*)&Bs[n * LDB + (t & 7) * 8] = v;
      }
    }
    __syncthreads();

#pragma unroll
    for (int ks = 0; ks < 2; ++ks) {
      short8 af[4], bf[4];
#pragma unroll
      for (int mi = 0; mi < 4; ++mi)
        af[mi] = *(const short8*)&As[(mi * 16 + lr) * LDA + ks * 32 + lk * 8];
#pragma unroll
      for (int ni = 0; ni < 4; ++ni)
        bf[ni] = *(const short8*)&Bs[(w * 64 + ni * 16 + lr) * LDB + ks * 32 + lk * 8];
#pragma unroll
      for (int mi = 0; mi < 4; ++mi)
#pragma unroll
        for (int ni = 0; ni < 4; ++ni)
          acc[mi][ni] = __builtin_amdgcn_mfma_f32_16x16x32_bf16(
              af[mi], bf[ni], acc[mi][ni], 0, 0, 0);
    }
    __syncthreads();
  }

  // ---------------- bias + ReLU -> Hs (bf16) ----------------
#pragma unroll
  for (int ni = 0; ni < 4; ++ni) {
    const int col = w * 64 + ni * 16 + lr;
    const float bias = b1[col];
#pragma unroll
    for (int mi = 0; mi < 4; ++mi) {
#pragma unroll
      for (int r = 0; r < 4; ++r) {
        float v = acc[mi][ni][r] + bias;
        v = v > 0.f ? v : 0.f;
        Hs[(mi * 16 + lk * 4 + r) * LDH + col] = f2b(v);
        acc[mi][ni][r] = 0.f;   // reset for GEMM2
      }
    }
  }
  __syncthreads();

  // ---------------- GEMM2: [64,256] @ [256,256] ----------------
  for (int kc = 0; kc < 4; ++kc) {
    {
      const unsigned short* wp = wt2 + kc * 64 + (t & 7) * 8;
      const int n0 = t >> 3;
#pragma unroll
      for (int i = 0; i < 8; ++i) {
        const int n = n0 + 32 * i;
        uint4 v = *(const uint4*)(wp + (size_t)n * 256);
        *(uint4*)&Bs[n * LDB + (t & 7) * 8] = v;
      }
    }
    __syncthreads();

#pragma unroll
    for (int ks = 0; ks < 2; ++ks) {
      short8 af[4], bf[4];
#pragma unroll
      for (int mi = 0; mi < 4; ++mi)
        af[mi] = *(const short8*)&Hs[(mi * 16 + lr) * LDH + kc * 64 + ks * 32 + lk * 8];
#pragma unroll
      for (int ni = 0; ni < 4; ++ni)
        bf[ni] = *(const short8*)&Bs[(w * 64 + ni * 16 + lr) * LDB + ks * 32 + lk * 8];
#pragma unroll
      for (int mi = 0; mi < 4; ++mi)
#pragma unroll
        for (int ni = 0; ni < 4; ++ni)
          acc[mi][ni] = __builtin_amdgcn_mfma_f32_16x16x32_bf16(
              af[mi], bf[ni], acc[mi][ni], 0, 0, 0);
    }
    __syncthreads();
  }

  // ---------------- bias + store f32 ----------------
#pragma unroll
  for (int ni = 0; ni < 4; ++ni) {
    const int col = w * 64 + ni * 16 + lr;
    const float bias = b2[col];
#pragma unroll
    for (int mi = 0; mi < 4; ++mi) {
#pragma unroll
      for (int r = 0; r < 4; ++r) {
        const int ee = ebase + mi * 16 + lk * 4 + r;
        if (ee < E) out[(size_t)ee * 256 + col] = acc[mi][ni][r] + bias;
      }
    }
  }
}

extern "C" void kernel_launch(void* const* d_in, const int* in_sizes, int n_in,
                              void* d_out, int out_size, void* d_ws, size_t ws_size,
                              hipStream_t stream) {
  const float* xnode = (const float*)d_in[0];
  const float* xedge = (const float*)d_in[1];
  const int* eidx = (const int*)d_in[2];
  const float* W1 = (const float*)d_in[3];
  const float* b1 = (const float*)d_in[4];
  const float* W2 = (const float*)d_in[5];
  const float* b2 = (const float*)d_in[6];
  float* out = (float*)d_out;

  const int NN = in_sizes[0] / 256;   // 50000
  const int E = in_sizes[1] / 256;    // 300000

  char* ws = (char*)d_ws;
  unsigned short* wt1 = (unsigned short*)ws;                        // 768*256*2 = 393216 B
  unsigned short* wt2 = (unsigned short*)(ws + 768 * 256 * 2);      // 256*256*2 = 131072 B
  unsigned short* nodeb = (unsigned short*)(ws + 768 * 256 * 2 + 256 * 256 * 2);
  const size_t need = (size_t)768 * 256 * 2 + 256 * 256 * 2 + (size_t)NN * 256 * 2;
  const int use_nodeb = (ws_size >= need) ? 1 : 0;

  transpose_w_kernel<<<(768 * 256 + 255) / 256, 256, 0, stream>>>(W1, wt1, 768, 256);
  transpose_w_kernel<<<(256 * 256 + 255) / 256, 256, 0, stream>>>(W2, wt2, 256, 256);
  if (use_nodeb) {
    const int n4 = NN * 64;  // NN*256/4 float4 chunks
    conv_bf16_kernel<<<(n4 + 255) / 256, 256, 0, stream>>>(xnode, nodeb, n4);
  }

  edge_mlp_kernel<<<(E + 63) / 64, 256, 0, stream>>>(
      xnode, xedge, eidx, nodeb, use_nodeb, wt1, b1, wt2, b2, out, E);
}

// Round 3
// 332.159 us; speedup vs baseline: 1.1764x; 1.1764x over previous
//
#include <hip/hip_runtime.h>

// EdgeBlock: out = relu(concat(xn[src], xn[dst], xe) @ W1 + b1) @ W2 + b2
// R3: BM=128/8-wave/BK=32 fused kernel; global_load_lds staging from pre-packed
// bf16 weights + bf16 node table; 2-phase double-buffer; swizzled Hs; LDS-staged
// coalesced f32 output.

typedef __attribute__((ext_vector_type(8))) short short8;   // MFMA A/B frag (8 bf16)
typedef __attribute__((ext_vector_type(4))) float f32x4;    // MFMA C/D frag

typedef __attribute__((address_space(1))) unsigned int* gp1_t;
typedef __attribute__((address_space(3))) unsigned int* lp3_t;

#define AS_OFF 0         // As: 2 x 8KB  (128 rows x 64B)
#define BS_OFF 16384     // Bs: 2 x 16KB (256 rows x 64B)
#define HS_OFF 49152     // Hs: 64KB     (128 rows x 512B, chunk-swizzled)
#define SMEM_SZ 114688   // 112KB -> 1 block/CU
#define LDO 260          // f32 out-stage row stride (256+4 pad)

__device__ __forceinline__ unsigned short f2b(float f) {
  unsigned int u = __float_as_uint(f);
  return (unsigned short)((u + 0x7FFFu + ((u >> 16) & 1u)) >> 16);
}
__device__ __forceinline__ unsigned int f2b2(float lo, float hi) {
  return (unsigned int)f2b(lo) | ((unsigned int)f2b(hi) << 16);
}
__device__ __forceinline__ void gload16(const void* g, void* l) {
  __builtin_amdgcn_global_load_lds((gp1_t)g, (lp3_t)l, 16, 0, 0);
}

// Pack W[k][256] -> wp[kc][n][kin] bf16 (chunk kc = 32 k-rows, contiguous 16KB)
__global__ void prep_w_kernel(const float* __restrict__ w,
                              unsigned short* __restrict__ wp, int total) {
  int i = blockIdx.x * 256 + threadIdx.x;
  if (i >= total) return;
  int kc = i >> 13;          // 8192 elems per chunk
  int rem = i & 8191;
  int n = rem >> 5;
  int kin = rem & 31;
  wp[i] = f2b(w[(size_t)(kc * 32 + kin) * 256 + n]);
}

__global__ void conv_bf16_kernel(const float* __restrict__ x,
                                 unsigned short* __restrict__ y, int n4) {
  int i = blockIdx.x * 256 + threadIdx.x;
  if (i >= n4) return;
  float4 v = ((const float4*)x)[i];
  ushort4 u;
  u.x = f2b(v.x); u.y = f2b(v.y); u.z = f2b(v.z); u.w = f2b(v.w);
  ((ushort4*)y)[i] = u;
}

__global__ __launch_bounds__(512, 2) void edge_mlp_kernel(
    const float* __restrict__ xnode, const float* __restrict__ xedge,
    const int* __restrict__ eidx,
    const unsigned short* __restrict__ nodeb, int use_nodeb,
    const unsigned short* __restrict__ wt1p, const float* __restrict__ b1,
    const unsigned short* __restrict__ wt2p, const float* __restrict__ b2,
    float* __restrict__ out, int E) {
  __shared__ __align__(16) char smem[SMEM_SZ];
  char* As = smem + AS_OFF;
  char* Bs = smem + BS_OFF;
  char* Hs = smem + HS_OFF;

  const int t = threadIdx.x;
  const int w = t >> 6, l = t & 63;
  const int lr = l & 15, lk = l >> 4;
  const int wr = w >> 2, wc = w & 3;     // wave grid 2(M) x 4(N)
  const int row4 = t >> 2;               // staging row 0..127
  const int c4 = t & 3;                  // staging 16B-chunk in row

  const int ebase = blockIdx.x * 128;
  int e = ebase + row4;
  if (e >= E) e = E - 1;                 // clamp tail; stores guarded
  const int isrc = eidx[e], idst = eidx[E + e];

  f32x4 acc[4][4];
#pragma unroll
  for (int i = 0; i < 4; ++i)
#pragma unroll
    for (int j = 0; j < 4; ++j) acc[i][j] = (f32x4)0.0f;

  // --- staging helpers ---
  // B chunk: 16KB linear from pre-packed weights (2 x gload16 per thread)
  auto stageB = [&](const unsigned short* wp, int kc, int buf) {
    const char* g = (const char*)wp + (size_t)kc * 16384 + t * 16;
    char* lb = Bs + buf * 16384 + (w << 10);       // wave-uniform base
    gload16(g, lb);
    gload16(g + 8192, lb + 8192);
  };
  // A node chunk: gathered bf16 rows, per-lane global addr, linear LDS dest
  auto stageA_node = [&](int kc, int buf) {
    const int node = (kc < 8) ? isrc : idst;
    const char* g = (const char*)nodeb + (size_t)node * 512 + (kc & 7) * 64 + c4 * 16;
    gload16(g, As + buf * 8192 + (w << 10));
  };
  // manual path (f32 source): issue loads early ...
  auto stageA_load = [&](int kc, float4& m0, float4& m1) {
    const float* src;
    if (kc < 8)        src = xnode + (size_t)isrc * 256 + kc * 32 + c4 * 8;
    else if (kc < 16)  src = xnode + (size_t)idst * 256 + (kc - 8) * 32 + c4 * 8;
    else               src = xedge + (size_t)e * 256 + (kc - 16) * 32 + c4 * 8;
    m0 = *(const float4*)src;
    m1 = *(const float4*)(src + 4);
  };
  // ... convert+write late (after compute), T14 split
  auto stageA_write = [&](int buf, float4 m0, float4 m1) {
    uint4 u;
    u.x = f2b2(m0.x, m0.y); u.y = f2b2(m0.z, m0.w);
    u.z = f2b2(m1.x, m1.y); u.w = f2b2(m1.z, m1.w);
    *(uint4*)(As + buf * 8192 + t * 16) = u;
  };

  auto compute1 = [&](int buf) {
    short8 af[4], bf[4];
    const char* ab = As + buf * 8192;
    const char* bb = Bs + buf * 16384;
#pragma unroll
    for (int mi = 0; mi < 4; ++mi)
      af[mi] = *(const short8*)(ab + (wr * 64 + mi * 16 + lr) * 64 + lk * 16);
#pragma unroll
    for (int ni = 0; ni < 4; ++ni)
      bf[ni] = *(const short8*)(bb + (wc * 64 + ni * 16 + lr) * 64 + lk * 16);
#pragma unroll
    for (int mi = 0; mi < 4; ++mi)
#pragma unroll
      for (int ni = 0; ni < 4; ++ni)
        acc[mi][ni] = __builtin_amdgcn_mfma_f32_16x16x32_bf16(
            af[mi], bf[ni], acc[mi][ni], 0, 0, 0);
  };

  // ---------------- GEMM1: 24 chunks of K=32, 2-phase dbuf ----------------
  stageB(wt1p, 0, 0);
  if (use_nodeb) {
    stageA_node(0, 0);
  } else {
    float4 a0, a1;
    stageA_load(0, a0, a1);
    stageA_write(0, a0, a1);
  }
  __syncthreads();

  for (int kc = 0; kc < 24; ++kc) {
    const int cur = kc & 1, nb = cur ^ 1;
    float4 m0, m1;
    bool man = false;
    if (kc < 23) {
      const int nk = kc + 1;
      stageB(wt1p, nk, nb);
      if (use_nodeb && nk < 16) {
        stageA_node(nk, nb);
      } else {
        stageA_load(nk, m0, m1);
        man = true;
      }
    } else {
      stageB(wt2p, 0, nb);   // prefetch W2 chunk 0 across the boundary
    }
    compute1(cur);
    if (man) stageA_write(nb, m0, m1);
    __syncthreads();
  }

  // ---------------- bias + ReLU -> Hs (bf16, chunk-swizzled) ----------------
#pragma unroll
  for (int ni = 0; ni < 4; ++ni) {
    const int col = wc * 64 + ni * 16 + lr;
    const float bias = b1[col];
    const int chunk = col >> 3;
    const int cb = (col & 7) * 2;
#pragma unroll
    for (int mi = 0; mi < 4; ++mi)
#pragma unroll
      for (int r = 0; r < 4; ++r) {
        const int row = wr * 64 + mi * 16 + lk * 4 + r;
        float v = acc[mi][ni][r] + bias;
        v = v > 0.f ? v : 0.f;
        *(unsigned short*)(Hs + row * 512 + ((chunk ^ (row & 7)) * 16) + cb) = f2b(v);
        acc[mi][ni][r] = 0.f;
      }
  }
  __syncthreads();

  // ---------------- GEMM2: 8 chunks of K=32, 2-phase dbuf ----------------
  for (int kc2 = 0; kc2 < 8; ++kc2) {
    const int cur = kc2 & 1, nb = cur ^ 1;
    if (kc2 < 7) stageB(wt2p, kc2 + 1, nb);
    {
      short8 af[4], bf[4];
      const char* bb = Bs + cur * 16384;
#pragma unroll
      for (int mi = 0; mi < 4; ++mi) {
        const int row = wr * 64 + mi * 16 + lr;
        af[mi] = *(const short8*)(Hs + row * 512 + (((kc2 * 4 + lk) ^ (row & 7)) * 16));
      }
#pragma unroll
      for (int ni = 0; ni < 4; ++ni)
        bf[ni] = *(const short8*)(bb + (wc * 64 + ni * 16 + lr) * 64 + lk * 16);
#pragma unroll
      for (int mi = 0; mi < 4; ++mi)
#pragma unroll
        for (int ni = 0; ni < 4; ++ni)
          acc[mi][ni] = __builtin_amdgcn_mfma_f32_16x16x32_bf16(
              af[mi], bf[ni], acc[mi][ni], 0, 0, 0);
    }
    __syncthreads();
  }

  // ---------------- bias + coalesced store via LDS f32 round-trip ----------------
  float* outst = (float*)smem;   // unions As+Bs+Hs (all dead now)
#pragma unroll
  for (int p = 0; p < 2; ++p) {
    __syncthreads();
    if (wr == p) {
#pragma unroll
      for (int ni = 0; ni < 4; ++ni) {
        const int col = wc * 64 + ni * 16 + lr;
        const float bias = b2[col];
#pragma unroll
        for (int mi = 0; mi < 4; ++mi)
#pragma unroll
          for (int r = 0; r < 4; ++r)
            outst[(mi * 16 + lk * 4 + r) * LDO + col] = acc[mi][ni][r] + bias;
      }
    }
    __syncthreads();
#pragma unroll
    for (int it = 0; it < 8; ++it) {
      const int idx = it * 2048 + t * 4;   // f32 index within 64x256 tile
      const int lrow = idx >> 8;
      const int cc = idx & 255;
      const int grow = ebase + p * 64 + lrow;
      if (grow < E)
        *(float4*)(out + (size_t)grow * 256 + cc) =
            *(const float4*)(outst + lrow * LDO + cc);
    }
  }
}

extern "C" void kernel_launch(void* const* d_in, const int* in_sizes, int n_in,
                              void* d_out, int out_size, void* d_ws, size_t ws_size,
                              hipStream_t stream) {
  const float* xnode = (const float*)d_in[0];
  const float* xedge = (const float*)d_in[1];
  const int* eidx = (const int*)d_in[2];
  const float* W1 = (const float*)d_in[3];
  const float* b1 = (const float*)d_in[4];
  const float* W2 = (const float*)d_in[5];
  const float* b2 = (const float*)d_in[6];
  float* out = (float*)d_out;

  const int NN = in_sizes[0] / 256;   // 50000
  const int E = in_sizes[1] / 256;    // 300000

  char* ws = (char*)d_ws;
  unsigned short* wt1p = (unsigned short*)ws;                       // 24 chunks = 384KB
  unsigned short* wt2p = (unsigned short*)(ws + 24 * 16384);        //  8 chunks = 128KB
  unsigned short* nodeb = (unsigned short*)(ws + 32 * 16384);       // NN*512B
  const size_t need = (size_t)32 * 16384 + (size_t)NN * 512;
  const int use_nodeb = (ws_size >= need) ? 1 : 0;

  prep_w_kernel<<<(24 * 8192 + 255) / 256, 256, 0, stream>>>(W1, wt1p, 24 * 8192);
  prep_w_kernel<<<(8 * 8192 + 255) / 256, 256, 0, stream>>>(W2, wt2p, 8 * 8192);
  if (use_nodeb) {
    const int n4 = NN * 64;
    conv_bf16_kernel<<<(n4 + 255) / 256, 256, 0, stream>>>(xnode, nodeb, n4);
  }

  edge_mlp_kernel<<<(E + 127) / 128, 512, 0, stream>>>(
      xnode, xedge, eidx, nodeb, use_nodeb, wt1p, b1, wt2p, b2, out, E);
}